// Round 1
// baseline (1877.508 us; speedup 1.0000x reference)
//
#include <hip/hip_runtime.h>
#include <math.h>

#define S_LEN 512
#define D_IN  768
#define H_DIM 50
#define G4    200      // 4*H
#define BROWS 128      // GEMM tile rows
#define BK    32       // GEMM K step

__device__ __forceinline__ float fsigmoid(float x) {
    return 1.0f / (1.0f + __expf(-x));
}
__device__ __forceinline__ float ftanh(float x) {
    float ax = fabsf(x);
    float e  = __expf(-2.0f * ax);
    float t  = (1.0f - e) / (1.0f + e);
    return copysignf(t, x);
}

// ---------------------------------------------------------------------------
// Kernel 1: xg[m][n] = sum_k x[m][k] * W_ih[n][k]   (bias added in scan)
// m = b*512 + t. Tile: 128 rows x 200 cols, 256 threads (4 waves).
// Wave w owns cols [50w, 50w+50); lane owns rows {lane, lane+64}.
// Tiles whose entire t-range is masked out are skipped (mask is monotone).
// ---------------------------------------------------------------------------
__global__ __launch_bounds__(256) void gemm_xg(
    const float* __restrict__ x, const int* __restrict__ mask,
    const float* __restrict__ W, float* __restrict__ xg)
{
    const int blk  = blockIdx.x;
    const int row0 = blk * BROWS;
    const int b    = row0 >> 9;      // /512
    const int t0   = row0 & 511;
    if (mask[b * S_LEN + t0] == 0) return;   // whole tile past length[b]

    __shared__ float As[BROWS][BK + 1];   // stride 33: (lane+k)%32 -> 2-way, free
    __shared__ float Bs[BK][202];         // stride 202: float2-aligned rows, 2-way writes

    const int tid     = threadIdx.x;
    const int wave    = tid >> 6;
    const int lane    = tid & 63;
    const int colBase = wave * 50;

    float acc0[50], acc1[50];
#pragma unroll
    for (int i = 0; i < 50; ++i) { acc0[i] = 0.f; acc1[i] = 0.f; }

    for (int k0 = 0; k0 < D_IN; k0 += BK) {
        // stage A tile: 128x32 = 4096 floats, 16/thread, coalesced rows
#pragma unroll
        for (int i = 0; i < 16; ++i) {
            int idx = tid + i * 256;
            int r = idx >> 5, k = idx & 31;
            As[r][k] = x[(size_t)(row0 + r) * D_IN + k0 + k];
        }
        // stage B tile transposed: Bs[k][n] = W[n][k0+k], 6400 floats, 25/thread
#pragma unroll
        for (int i = 0; i < 25; ++i) {
            int idx = tid + i * 256;
            int n = idx >> 5, k = idx & 31;
            Bs[k][n] = W[(size_t)n * D_IN + k0 + k];
        }
        __syncthreads();
#pragma unroll
        for (int kk = 0; kk < BK; ++kk) {
            float a0 = As[lane][kk];
            float a1 = As[lane + 64][kk];
            const float2* brow = (const float2*)&Bs[kk][colBase]; // wave-uniform (broadcast)
#pragma unroll
            for (int p = 0; p < 25; ++p) {
                float2 bv = brow[p];
                acc0[2*p]     += a0 * bv.x;
                acc0[2*p + 1] += a0 * bv.y;
                acc1[2*p]     += a1 * bv.x;
                acc1[2*p + 1] += a1 * bv.y;
            }
        }
        __syncthreads();
    }

    size_t o0 = (size_t)(row0 + lane)      * G4 + colBase;
    size_t o1 = (size_t)(row0 + lane + 64) * G4 + colBase;
#pragma unroll
    for (int p = 0; p < 25; ++p) {
        ((float2*)&xg[o0])[p] = make_float2(acc0[2*p], acc0[2*p + 1]);
        ((float2*)&xg[o1])[p] = make_float2(acc1[2*p], acc1[2*p + 1]);
    }
}

// ---------------------------------------------------------------------------
// Kernel 2: sequential LSTM scan + classifier head. One block per batch b.
// 256 threads: threads 0..199 are "gate" threads (one per gate row of W_hh,
// W_hh row held in 50 VGPRs). h lives in LDS (broadcast reads). c lives in
// registers of threads 0..49. xg_t loads are 3-deep software-prefetched.
// ---------------------------------------------------------------------------
__global__ __launch_bounds__(256) void lstm_scan(
    const float* __restrict__ xg, const int* __restrict__ mask,
    const float* __restrict__ W_hh, const float* __restrict__ b_ih,
    const float* __restrict__ b_hh, const float* __restrict__ W_cls,
    const float* __restrict__ b_cls, float* __restrict__ out)
{
    const int b    = blockIdx.x;
    const int tid  = threadIdx.x;
    const int lane = tid & 63;
    const int wid  = tid >> 6;

    __shared__ int   red[4];
    __shared__ int   len_sh;
    __shared__ float __align__(16) h_sh[52];
    __shared__ float gates[200];

    // length[b] = sum(mask[b, :])
    int s = mask[b * S_LEN + tid] + mask[b * S_LEN + tid + 256];
#pragma unroll
    for (int off = 32; off > 0; off >>= 1) s += __shfl_down(s, off, 64);
    if (lane == 0) red[wid] = s;
    if (tid < 52) h_sh[tid] = 0.f;
    __syncthreads();
    if (tid == 0) len_sh = red[0] + red[1] + red[2] + red[3];
    __syncthreads();
    const int len = len_sh;

    const bool gthread = (tid < G4);
    float w[50];
    float bias = 0.f;
    if (gthread) {
        const float2* wr = (const float2*)&W_hh[tid * H_DIM];
#pragma unroll
        for (int p = 0; p < 25; ++p) { float2 v = wr[p]; w[2*p] = v.x; w[2*p+1] = v.y; }
        bias = b_ih[tid] + b_hh[tid];
    }
    float c = 0.f;

    const float* xgb = xg + (size_t)b * S_LEN * G4;

    float p0 = 0.f, p1 = 0.f, p2 = 0.f;
    if (gthread) {
        p0 = xgb[tid];
        if (len > 1) p1 = xgb[(size_t)1 * G4 + tid];
        if (len > 2) p2 = xgb[(size_t)2 * G4 + tid];
    }

    auto body = [&](int t, float xv) {
        if (gthread) {
            float acc = xv + bias;
            const float2* h2 = (const float2*)h_sh;   // broadcast reads
#pragma unroll
            for (int p = 0; p < 25; ++p) {
                float2 hv = h2[p];
                acc += hv.x * w[2*p] + hv.y * w[2*p + 1];
            }
            float av = (tid >= 100 && tid < 150) ? ftanh(acc) : fsigmoid(acc);
            gates[tid] = av;
        }
        __syncthreads();
        if (tid < H_DIM) {
            float ig = gates[tid], fg = gates[50 + tid];
            float gg = gates[100 + tid], og = gates[150 + tid];
            c = fg * c + ig * gg;
            h_sh[tid] = og * ftanh(c);
        }
        __syncthreads();
    };

    for (int t = 0; t < len; t += 3) {
        body(t, p0);
        if (gthread && t + 3 < len) p0 = xgb[(size_t)(t + 3) * G4 + tid];
        if (t + 1 < len) {
            body(t + 1, p1);
            if (gthread && t + 4 < len) p1 = xgb[(size_t)(t + 4) * G4 + tid];
        }
        if (t + 2 < len) {
            body(t + 2, p2);
            if (gthread && t + 5 < len) p2 = xgb[(size_t)(t + 5) * G4 + tid];
        }
    }

    // classifier head: out[b][cls] = b_cls[cls] + sum_j h[j] * W_cls[cls][j]
    if (tid < 2) {
        float accv = b_cls[tid];
#pragma unroll
        for (int j = 0; j < H_DIM; ++j) accv += h_sh[j] * W_cls[tid * H_DIM + j];
        out[b * 2 + tid] = accv;
    }
}

extern "C" void kernel_launch(void* const* d_in, const int* in_sizes, int n_in,
                              void* d_out, int out_size, void* d_ws, size_t ws_size,
                              hipStream_t stream) {
    const float* x     = (const float*)d_in[0];
    const int*   mask  = (const int*)  d_in[1];
    const float* W_ih  = (const float*)d_in[2];
    const float* W_hh  = (const float*)d_in[3];
    const float* b_ih  = (const float*)d_in[4];
    const float* b_hh  = (const float*)d_in[5];
    const float* W_cls = (const float*)d_in[6];
    const float* b_cls = (const float*)d_in[7];
    float* out = (float*)d_out;
    float* xg  = (float*)d_ws;   // needs 256*512*200*4 = 104.9 MB

    hipLaunchKernelGGL(gemm_xg, dim3((256 * S_LEN) / BROWS), dim3(256), 0, stream,
                       x, mask, W_ih, xg);
    hipLaunchKernelGGL(lstm_scan, dim3(256), dim3(256), 0, stream,
                       xg, mask, W_hh, b_ih, b_hh, W_cls, b_cls, out);
}

// Round 2
// 703.014 us; speedup vs baseline: 2.6707x; 2.6707x over previous
//
#include <hip/hip_runtime.h>
#include <math.h>

#define S_LEN 512
#define D_IN  768
#define H_DIM 50
#define G4    200
#define BROWS 128
#define BK    32
#define NTILES ((256 * S_LEN) / BROWS)   // 1024

__device__ __forceinline__ float fsigmoid(float x) {
    return 1.0f / (1.0f + __expf(-x));
}
__device__ __forceinline__ float ftanh(float x) {
    float ax = fabsf(x);
    float e  = __expf(-2.0f * ax);
    float t  = (1.0f - e) / (1.0f + e);
    return copysignf(t, x);
}

// ---------------------------------------------------------------------------
// Kernel 1: xg[m][n] = sum_k x[m][k] * W_ih[n][k].  Persistent blocks pull
// 128-row tiles off an atomic queue (load balance: ~40% of tiles are dead via
// the monotone mask and static mapping left CUs idle -> 7.5% occupancy).
// Inner loop: B broadcast via float4 (13 LDS instrs/kk instead of 27) keeps
// the per-CU LDS pipe under the VALU wall. Bs slices padded to 52 floats so
// every wave's 50-col slice is 16B-aligned for ds_read_b128.
// ---------------------------------------------------------------------------
template<bool QUEUE>
__global__ __launch_bounds__(256, 2) void gemm_xg(
    const float* __restrict__ x, const int* __restrict__ mask,
    const float* __restrict__ W, float* __restrict__ xg, int* counter)
{
    __shared__ float __align__(16) As[BROWS][33];   // (lane+kk)%32 -> 2-way, free
    __shared__ float __align__(16) Bs[BK][212];     // 4 slices * 52 floats, 16B-aligned
    __shared__ int tile_sh;

    const int tid  = threadIdx.x;
    const int wave = tid >> 6;
    const int lane = tid & 63;

    for (;;) {
        int tile;
        if (QUEUE) {
            if (tid == 0) tile_sh = atomicAdd(counter, 1);
            __syncthreads();
            tile = tile_sh;
            __syncthreads();   // protect tile_sh from next-iter overwrite
            if (tile >= NTILES) return;
        } else {
            tile = blockIdx.x;
        }
        const int row0 = tile * BROWS;
        const int b    = row0 >> 9;
        const int t0   = row0 & (S_LEN - 1);

        if (mask[b * S_LEN + t0] != 0) {
            float acc0[50], acc1[50];
#pragma unroll
            for (int i = 0; i < 50; ++i) { acc0[i] = 0.f; acc1[i] = 0.f; }

            for (int k0 = 0; k0 < D_IN; k0 += BK) {
                // stage A: 128x32 floats, float4 global loads, coalesced
#pragma unroll
                for (int i = 0; i < 4; ++i) {
                    int f = i * 256 + tid, r = f >> 3, q = f & 7;
                    float4 v = *(const float4*)&x[(size_t)(row0 + r) * D_IN + k0 + q * 4];
                    As[r][q * 4 + 0] = v.x; As[r][q * 4 + 1] = v.y;
                    As[r][q * 4 + 2] = v.z; As[r][q * 4 + 3] = v.w;
                }
                // stage B transposed: Bs[k][slice(n)] = W[n][k0+k]
#pragma unroll
                for (int i = 0; i < 25; ++i) {
                    int idx = i * 256 + tid, n = idx >> 5, k = idx & 31;
                    int s = n / 50, j = n - s * 50;
                    Bs[k][s * 52 + j] = W[(size_t)n * D_IN + k0 + k];
                }
                __syncthreads();
#pragma unroll
                for (int kk = 0; kk < BK; ++kk) {
                    float a0 = As[lane][kk];
                    float a1 = As[lane + 64][kk];
                    const float4* brow = (const float4*)&Bs[kk][wave * 52]; // broadcast b128
#pragma unroll
                    for (int p = 0; p < 12; ++p) {
                        float4 bv = brow[p];
                        acc0[4*p+0] += a0 * bv.x; acc0[4*p+1] += a0 * bv.y;
                        acc0[4*p+2] += a0 * bv.z; acc0[4*p+3] += a0 * bv.w;
                        acc1[4*p+0] += a1 * bv.x; acc1[4*p+1] += a1 * bv.y;
                        acc1[4*p+2] += a1 * bv.z; acc1[4*p+3] += a1 * bv.w;
                    }
                    float2 bt = *(const float2*)&Bs[kk][wave * 52 + 48];
                    acc0[48] += a0 * bt.x; acc0[49] += a0 * bt.y;
                    acc1[48] += a1 * bt.x; acc1[49] += a1 * bt.y;
                }
                __syncthreads();
            }
            size_t o0 = (size_t)(row0 + lane)      * G4 + wave * 50;
            size_t o1 = (size_t)(row0 + lane + 64) * G4 + wave * 50;
#pragma unroll
            for (int p = 0; p < 25; ++p) {
                ((float2*)&xg[o0])[p] = make_float2(acc0[2*p], acc0[2*p+1]);
                ((float2*)&xg[o1])[p] = make_float2(acc1[2*p], acc1[2*p+1]);
            }
        }
        if (!QUEUE) return;
    }
}

// ---------------------------------------------------------------------------
// Kernel 2: sequential LSTM scan + classifier head. One block per batch b.
// Gate threads (0..199) hold their W_hh row in 50 VGPRs; matvec uses 4 split
// accumulators (the serial 50-FMA chain was 200 cyc of the step critical
// path) and float4 h broadcasts. xg loads are 3-deep prefetched.
// ---------------------------------------------------------------------------
__global__ __launch_bounds__(256) void lstm_scan(
    const float* __restrict__ xg, const int* __restrict__ mask,
    const float* __restrict__ W_hh, const float* __restrict__ b_ih,
    const float* __restrict__ b_hh, const float* __restrict__ W_cls,
    const float* __restrict__ b_cls, float* __restrict__ out)
{
    const int b    = blockIdx.x;
    const int tid  = threadIdx.x;
    const int lane = tid & 63;
    const int wid  = tid >> 6;

    __shared__ int   red[4];
    __shared__ int   len_sh;
    __shared__ float __align__(16) h_sh[52];
    __shared__ float gates[200];

    int s = mask[b * S_LEN + tid] + mask[b * S_LEN + tid + 256];
#pragma unroll
    for (int off = 32; off > 0; off >>= 1) s += __shfl_down(s, off, 64);
    if (lane == 0) red[wid] = s;
    if (tid < 52) h_sh[tid] = 0.f;
    __syncthreads();
    if (tid == 0) len_sh = red[0] + red[1] + red[2] + red[3];
    __syncthreads();
    const int len = len_sh;

    const bool gthread = (tid < G4);
    float w[50];
    float bias = 0.f;
    if (gthread) {
        const float2* wr = (const float2*)&W_hh[tid * H_DIM];
#pragma unroll
        for (int p = 0; p < 25; ++p) { float2 v = wr[p]; w[2*p] = v.x; w[2*p+1] = v.y; }
        bias = b_ih[tid] + b_hh[tid];
    }
    float c = 0.f;

    const float* xgb = xg + (size_t)b * S_LEN * G4;

    float p0 = 0.f, p1 = 0.f, p2 = 0.f;
    if (gthread) {
        p0 = xgb[tid];
        if (len > 1) p1 = xgb[(size_t)1 * G4 + tid];
        if (len > 2) p2 = xgb[(size_t)2 * G4 + tid];
    }

    auto body = [&](int t, float xv) {
        if (gthread) {
            const float4* h4 = (const float4*)h_sh;
            float s0 = 0.f, s1 = 0.f, s2 = 0.f, s3 = 0.f;
#pragma unroll
            for (int p = 0; p < 12; ++p) {
                float4 hv = h4[p];
                s0 += hv.x * w[4*p+0]; s1 += hv.y * w[4*p+1];
                s2 += hv.z * w[4*p+2]; s3 += hv.w * w[4*p+3];
            }
            float2 ht = *(const float2*)&h_sh[48];
            s0 += ht.x * w[48]; s1 += ht.y * w[49];
            float acc = xv + bias + (s0 + s1) + (s2 + s3);
            float av = (tid >= 100 && tid < 150) ? ftanh(acc) : fsigmoid(acc);
            gates[tid] = av;
        }
        __syncthreads();
        if (tid < H_DIM) {
            float ig = gates[tid], fg = gates[50 + tid];
            float gg = gates[100 + tid], og = gates[150 + tid];
            c = fg * c + ig * gg;
            h_sh[tid] = og * ftanh(c);
        }
        __syncthreads();
    };

    for (int t = 0; t < len; t += 3) {
        body(t, p0);
        if (gthread && t + 3 < len) p0 = xgb[(size_t)(t + 3) * G4 + tid];
        if (t + 1 < len) {
            body(t + 1, p1);
            if (gthread && t + 4 < len) p1 = xgb[(size_t)(t + 4) * G4 + tid];
        }
        if (t + 2 < len) {
            body(t + 2, p2);
            if (gthread && t + 5 < len) p2 = xgb[(size_t)(t + 5) * G4 + tid];
        }
    }

    if (tid < 2) {
        float accv = b_cls[tid];
#pragma unroll
        for (int j = 0; j < H_DIM; ++j) accv += h_sh[j] * W_cls[tid * H_DIM + j];
        out[b * 2 + tid] = accv;
    }
}

extern "C" void kernel_launch(void* const* d_in, const int* in_sizes, int n_in,
                              void* d_out, int out_size, void* d_ws, size_t ws_size,
                              hipStream_t stream) {
    const float* x     = (const float*)d_in[0];
    const int*   mask  = (const int*)  d_in[1];
    const float* W_ih  = (const float*)d_in[2];
    const float* W_hh  = (const float*)d_in[3];
    const float* b_ih  = (const float*)d_in[4];
    const float* b_hh  = (const float*)d_in[5];
    const float* W_cls = (const float*)d_in[6];
    const float* b_cls = (const float*)d_in[7];
    float* out = (float*)d_out;
    float* xg  = (float*)d_ws;

    const size_t xg_bytes = (size_t)256 * S_LEN * G4 * sizeof(float);  // 104.9 MB

    if (ws_size >= xg_bytes + 64) {
        int* counter = (int*)((char*)d_ws + xg_bytes);
        hipMemsetAsync(counter, 0, sizeof(int), stream);   // capture-safe, stream-ordered
        hipLaunchKernelGGL((gemm_xg<true>), dim3(1024), dim3(256), 0, stream,
                           x, mask, W_ih, xg, counter);
    } else {
        hipLaunchKernelGGL((gemm_xg<false>), dim3(NTILES), dim3(256), 0, stream,
                           x, mask, W_ih, xg, nullptr);
    }
    hipLaunchKernelGGL(lstm_scan, dim3(256), dim3(256), 0, stream,
                       xg, mask, W_hh, b_ih, b_hh, W_cls, b_cls, out);
}